// Round 1
// baseline (475.022 us; speedup 1.0000x reference)
//
#include <hip/hip_runtime.h>
#include <stdint.h>

typedef unsigned short u16;
typedef uint32_t u32;

typedef short s16x8 __attribute__((ext_vector_type(8)));  // 8 bf16 for MFMA A/B frag
typedef float f32x4 __attribute__((ext_vector_type(4)));
typedef u32   u32x4 __attribute__((ext_vector_type(4)));
typedef u16   u16x4 __attribute__((ext_vector_type(4)));

constexpr int BB = 8, LL = 2048, DD = 1024, HH = 512, NN = 64;
constexpr int MT = BB * LL;   // 16384 rows
constexpr int LKK = 128;      // truncated SSM kernel taps (decay => tail < 1e-6)

static __device__ __forceinline__ u16 f2bf(float f) {
  u32 u = __float_as_uint(f);
  u32 r = (u + 0x7FFFu + ((u >> 16) & 1u)) >> 16;  // RNE
  return (u16)r;
}
static __device__ __forceinline__ float bf2f(u16 v) {
  return __uint_as_float(((u32)v) << 16);
}

// ---------------------------------------------------------------------------
// Transpose + cast 1024x1024 fp32 weights to bf16 in [N][K] (B^T) layout.
__global__ __launch_bounds__(256)
void wtrans_kernel(const float* __restrict__ w_in, const float* __restrict__ w_out,
                   u16* __restrict__ wt_in, u16* __restrict__ wt_out) {
  __shared__ float tile[32][33];
  const float* src = blockIdx.z ? w_out : w_in;
  u16* dst = blockIdx.z ? wt_out : wt_in;
  int n0 = blockIdx.x * 32, k0 = blockIdx.y * 32;
  int tx = threadIdx.x, ty = threadIdx.y;
#pragma unroll
  for (int i = 0; i < 32; i += 8)
    tile[ty + i][tx] = src[(size_t)(k0 + ty + i) * DD + n0 + tx];
  __syncthreads();
#pragma unroll
  for (int i = 0; i < 32; i += 8)
    dst[(size_t)(n0 + ty + i) * DD + k0 + tx] = f2bf(tile[tx][ty + i]);
}

// ---------------------------------------------------------------------------
// x fp32 -> bf16
__global__ __launch_bounds__(256)
void xcast_kernel(const float* __restrict__ x, u16* __restrict__ xb) {
  size_t i = (size_t)(blockIdx.x * 256 + threadIdx.x) * 4;
  float4 v = *(const float4*)(x + i);
  u16x4 o;
  o[0] = f2bf(v.x); o[1] = f2bf(v.y); o[2] = f2bf(v.z); o[3] = f2bf(v.w);
  *(u16x4*)(xb + i) = o;
}

// ---------------------------------------------------------------------------
// depthwise circular conv (K=4, pads 1/2) + SiLU -> bf16. one block per (b,t) row.
__global__ __launch_bounds__(256)
void convsilu_kernel(const float* __restrict__ g, const float* __restrict__ ck,
                     const float* __restrict__ cb, u16* __restrict__ gp) {
  int bt = blockIdx.x;
  int b = bt >> 11, t = bt & (LL - 1);
  int d = threadIdx.x * 4;
  const float* gb = g + (size_t)b * LL * DD;
  int tm1 = (t + LL - 1) & (LL - 1);
  int tp1 = (t + 1) & (LL - 1);
  int tp2 = (t + 2) & (LL - 1);
  float4 a0 = *(const float4*)(gb + (size_t)tm1 * DD + d);
  float4 a1 = *(const float4*)(gb + (size_t)t   * DD + d);
  float4 a2 = *(const float4*)(gb + (size_t)tp1 * DD + d);
  float4 a3 = *(const float4*)(gb + (size_t)tp2 * DD + d);
  float4 k0 = *(const float4*)(ck + d);
  float4 k1 = *(const float4*)(ck + DD + d);
  float4 k2 = *(const float4*)(ck + 2 * DD + d);
  float4 k3 = *(const float4*)(ck + 3 * DD + d);
  float4 bi = *(const float4*)(cb + d);
  float v0 = a0.x*k0.x + a1.x*k1.x + a2.x*k2.x + a3.x*k3.x + bi.x;
  float v1 = a0.y*k0.y + a1.y*k1.y + a2.y*k2.y + a3.y*k3.y + bi.y;
  float v2 = a0.z*k0.z + a1.z*k1.z + a2.z*k2.z + a3.z*k3.z + bi.z;
  float v3 = a0.w*k0.w + a1.w*k1.w + a2.w*k2.w + a3.w*k3.w + bi.w;
  u16x4 o;
  o[0] = f2bf(v0 / (1.f + expf(-v0)));
  o[1] = f2bf(v1 / (1.f + expf(-v1)));
  o[2] = f2bf(v2 / (1.f + expf(-v2)));
  o[3] = f2bf(v3 / (1.f + expf(-v3)));
  *(u16x4*)(gp + (size_t)bt * DD + d) = o;
}

// ---------------------------------------------------------------------------
// S4D kernel: Kt[j][h] = packed bf16 (re | im<<16) of sum_n (w_re+i w_im)*exp(A*j)
__global__ __launch_bounds__(128)
void kgen_kernel(const float* __restrict__ ldk, const float* __restrict__ fq,
                 const float* __restrict__ wre, const float* __restrict__ wim,
                 u32* __restrict__ Kt) {
  int h = blockIdx.x, j = threadIdx.x;
  __shared__ float sr[NN], sf[NN], sa[NN], sb[NN];
  if (j < NN) {
    sr[j] = expf(ldk[h * NN + j]);  // decay rate
    sf[j] = fq[h * NN + j];
    sa[j] = wre[h * NN + j];
    sb[j] = wim[h * NN + j];
  }
  __syncthreads();
  float t = (float)j;
  float re = 0.f, im = 0.f;
  for (int n = 0; n < NN; ++n) {
    float e = expf(-sr[n] * t);
    float s, c;
    sincosf(sf[n] * t, &s, &c);
    re += e * (sa[n] * c - sb[n] * s);
    im += e * (sa[n] * s + sb[n] * c);
  }
  Kt[(size_t)j * HH + h] = (u32)f2bf(re) | ((u32)f2bf(im) << 16);
}

// ---------------------------------------------------------------------------
// bf16 MFMA GEMM: C[M,N] = A[M,K] @ Bt[N,K]^T, 128x128 tile, BK=32, 4 waves 2x2.
// EPI=0: C *= gmul (bf16), store bf16.  EPI=1: store fp32.
template <int EPI>
__global__ __launch_bounds__(256)
void gemm_kernel(const u16* __restrict__ A, const u16* __restrict__ Bt,
                 const u16* __restrict__ gmul, void* __restrict__ out) {
  constexpr int K = DD;
  __shared__ __align__(16) u16 As[128 * 32];  // fragment-order: slot = frag*64+lane, 8 bf16
  __shared__ __align__(16) u16 Bs[128 * 32];
  int tid = threadIdx.x;
  int lane = tid & 63, w = tid >> 6;
  int wm = w & 1, wn = w >> 1;
  int lm = lane & 15, lk = lane >> 4;
  int n0 = blockIdx.x * 128, m0 = blockIdx.y * 128;

  f32x4 acc[4][4] = {};

  const u16* pa = A + (size_t)(m0 + lm) * K + lk * 8;
  const u16* pb = Bt + (size_t)(n0 + lm) * K + lk * 8;

  for (int k0 = 0; k0 < K; k0 += 32) {
    __syncthreads();
#pragma unroll
    for (int i = 0; i < 2; ++i) {
      int f = w + i * 4;  // fragment index 0..7 (rows f*16..f*16+15)
      u32x4 va = *(const u32x4*)(pa + (size_t)f * 16 * K + k0);
      u32x4 vb = *(const u32x4*)(pb + (size_t)f * 16 * K + k0);
      *(u32x4*)(As + (i * 256 + w * 64 + lane) * 8) = va;
      *(u32x4*)(Bs + (i * 256 + w * 64 + lane) * 8) = vb;
    }
    __syncthreads();
    s16x8 af[4], bfr[4];
#pragma unroll
    for (int i = 0; i < 4; ++i)
      af[i] = *(const s16x8*)(As + ((wm * 4 + i) * 64 + lane) * 8);
#pragma unroll
    for (int j = 0; j < 4; ++j)
      bfr[j] = *(const s16x8*)(Bs + ((wn * 4 + j) * 64 + lane) * 8);
#pragma unroll
    for (int i = 0; i < 4; ++i)
#pragma unroll
      for (int j = 0; j < 4; ++j)
        acc[i][j] = __builtin_amdgcn_mfma_f32_16x16x32_bf16(af[i], bfr[j], acc[i][j], 0, 0, 0);
  }

  // C/D layout: col = lane&15, row = (lane>>4)*4 + reg   [guide §3, m89-verified]
  int rb = (lane >> 4) * 4, col = lane & 15;
#pragma unroll
  for (int i = 0; i < 4; ++i) {
#pragma unroll
    for (int j = 0; j < 4; ++j) {
      int mg = m0 + wm * 64 + i * 16 + rb;
      int ng = n0 + wn * 64 + j * 16 + col;
#pragma unroll
      for (int r = 0; r < 4; ++r) {
        size_t idx = (size_t)(mg + r) * DD + ng;
        float v = acc[i][j][r];
        if (EPI == 0) {
          ((u16*)out)[idx] = f2bf(v * bf2f(gmul[idx]));
        } else {
          ((float*)out)[idx] = v;
        }
      }
    }
  }
}

// ---------------------------------------------------------------------------
// Truncated causal complex conv: y[b,t,h] = sum_{j<128} K[h,j] * u_c[b,t-j,h].
// Block: one b, 32 h's, 128 t's. u window + K staged in LDS (packed bf16 pairs).
// Each thread: 1 h, 16 consecutive t, register sliding window of 31 complex u's.
__global__ __launch_bounds__(256)
void ssmconv_kernel(const u16* __restrict__ u, const u32* __restrict__ Kt,
                    u16* __restrict__ y) {
  __shared__ u32 Us[256 * 32];   // [row s-rel][h]  (re lo16 | im hi16)   32 KB
  __shared__ u32 Ks[LKK * 32];   // [j][h]                                16 KB
  int tid = threadIdx.x;
  int t0 = blockIdx.x * 128;
  int h0 = blockIdx.y * 32;
  int b  = blockIdx.z;

  // stage K slab (global already [j][H] packed): coalesced uint4
  {
    int c = tid & 7, j0 = tid >> 3;
    for (int j = j0; j < LKK; j += 32) {
      u32x4 v = *(const u32x4*)(Kt + (size_t)j * HH + h0 + c * 4);
      *(u32x4*)(Ks + j * 32 + c * 4) = v;
    }
  }
  // stage u rows: row r <-> s = t0-128+r ; zero-fill s<0 (causal start)
  {
    int c = tid & 7, r0 = tid >> 3;
    for (int r = r0; r < 256; r += 32) {
      int s = t0 - 128 + r;
      u32x4 pk = {};
      if (s >= 0) {
        const u16* ur = u + (size_t)(b * LL + s) * DD;
        u16x4 re = *(const u16x4*)(ur + h0 + c * 4);
        u16x4 im = *(const u16x4*)(ur + h0 + 512 + c * 4);
        pk[0] = re[0] | ((u32)im[0] << 16);
        pk[1] = re[1] | ((u32)im[1] << 16);
        pk[2] = re[2] | ((u32)im[2] << 16);
        pk[3] = re[3] | ((u32)im[3] << 16);
      }
      *(u32x4*)(Us + r * 32 + c * 4) = pk;
    }
  }
  __syncthreads();

  int h = tid & 31, tg = tid >> 5;
  int tl0 = tg * 16;
  float2 acc[16];
#pragma unroll
  for (int i = 0; i < 16; ++i) acc[i] = make_float2(0.f, 0.f);

  float2 W[31];
  int base = 128 + tl0 - 15;
#pragma unroll
  for (int i = 0; i < 31; ++i) {
    u32 v = Us[(base + i) * 32 + h];
    W[i] = make_float2(__uint_as_float(v << 16), __uint_as_float(v & 0xFFFF0000u));
  }
#pragma unroll 1
  for (int jb = 0; jb < 8; ++jb) {
#pragma unroll
    for (int jj = 0; jj < 16; ++jj) {
      u32 kp = Ks[(jb * 16 + jj) * 32 + h];
      float kre = __uint_as_float(kp << 16);
      float kim = __uint_as_float(kp & 0xFFFF0000u);
#pragma unroll
      for (int toff = 0; toff < 16; ++toff) {
        float2 uv = W[15 + toff - jj];
        acc[toff].x = fmaf(kre, uv.x, fmaf(-kim, uv.y, acc[toff].x));
        acc[toff].y = fmaf(kre, uv.y, fmaf(kim, uv.x, acc[toff].y));
      }
    }
    if (jb < 7) {
#pragma unroll
      for (int i = 30; i >= 16; --i) W[i] = W[i - 16];
      base -= 16;
#pragma unroll
      for (int i = 0; i < 16; ++i) {
        u32 v = Us[(base + i) * 32 + h];
        W[i] = make_float2(__uint_as_float(v << 16), __uint_as_float(v & 0xFFFF0000u));
      }
    }
  }
  u16* yr = y + (size_t)(b * LL + t0 + tl0) * DD;
#pragma unroll
  for (int toff = 0; toff < 16; ++toff) {
    yr[(size_t)toff * DD + h0 + h]       = f2bf(acc[toff].x);  // real -> ch [0,512)
    yr[(size_t)toff * DD + h0 + 512 + h] = f2bf(acc[toff].y);  // imag -> ch [512,1024)
  }
}

// ---------------------------------------------------------------------------
extern "C" void kernel_launch(void* const* d_in, const int* in_sizes, int n_in,
                              void* d_out, int out_size, void* d_ws, size_t ws_size,
                              hipStream_t stream) {
  (void)in_sizes; (void)n_in; (void)out_size; (void)ws_size;
  const float* x    = (const float*)d_in[0];
  const float* g    = (const float*)d_in[1];
  const float* win  = (const float*)d_in[2];
  const float* ck   = (const float*)d_in[3];
  const float* cb   = (const float*)d_in[4];
  const float* ldk  = (const float*)d_in[5];
  const float* fq   = (const float*)d_in[6];
  const float* wre  = (const float*)d_in[7];
  const float* wim  = (const float*)d_in[8];
  const float* wout = (const float*)d_in[9];

  char* ws = (char*)d_ws;
  const size_t SZ = (size_t)MT * DD * 2;           // 32 MB per bf16 tensor
  u16* xb  = (u16*)(ws);
  u16* gp  = (u16*)(ws + SZ);
  u16* ub  = (u16*)(ws + 2 * SZ);
  u16* yb  = (u16*)(ws + 3 * SZ);
  u16* wti = (u16*)(ws + 4 * SZ);
  u16* wto = (u16*)(ws + 4 * SZ + (1 << 21));
  u32* Kt  = (u32*)(ws + 4 * SZ + (2 << 21));      // 256 KB; total ~138.5 MB

  wtrans_kernel<<<dim3(32, 32, 2), dim3(32, 8), 0, stream>>>(win, wout, wti, wto);
  xcast_kernel<<<dim3(MT * DD / 1024), dim3(256), 0, stream>>>(x, xb);
  convsilu_kernel<<<dim3(MT), dim3(256), 0, stream>>>(g, ck, cb, gp);
  kgen_kernel<<<dim3(HH), dim3(128), 0, stream>>>(ldk, fq, wre, wim, Kt);
  gemm_kernel<0><<<dim3(8, 128), dim3(256), 0, stream>>>(xb, wti, gp, ub);
  ssmconv_kernel<<<dim3(16, 16, 8), dim3(256), 0, stream>>>(ub, Kt, yb);
  gemm_kernel<1><<<dim3(8, 128), dim3(256), 0, stream>>>(yb, wto, nullptr, d_out);
}

// Round 2
// 438.161 us; speedup vs baseline: 1.0841x; 1.0841x over previous
//
#include <hip/hip_runtime.h>
#include <stdint.h>

typedef unsigned short u16;
typedef uint32_t u32;
typedef _Float16 f16;

typedef short s16x8 __attribute__((ext_vector_type(8)));  // 8 bf16 for MFMA A/B frag
typedef float f32x4 __attribute__((ext_vector_type(4)));
typedef u32   u32x4 __attribute__((ext_vector_type(4)));
typedef u32   u32x2 __attribute__((ext_vector_type(2)));
typedef u16   u16x4 __attribute__((ext_vector_type(4)));
typedef f16   h2    __attribute__((ext_vector_type(2)));

typedef __attribute__((address_space(1))) const u32 gu32;
typedef __attribute__((address_space(3))) u32 lu32;

constexpr int BB = 8, LL = 2048, DD = 1024, HH = 512, NN = 64;
constexpr int MT = BB * LL;   // 16384 rows
constexpr int LKK = 128;      // truncated SSM kernel taps (decay => tail < 1e-6)

static __device__ __forceinline__ u16 f2bf(float f) {
  u32 u = __float_as_uint(f);
  u32 r = (u + 0x7FFFu + ((u >> 16) & 1u)) >> 16;  // RNE
  return (u16)r;
}
static __device__ __forceinline__ u16 f2h(float f) {
  f16 h = (f16)f; union { u16 u; f16 h; } x; x.h = h; return x.u;
}
static __device__ __forceinline__ float h2f(u16 v) {
  union { u16 u; f16 h; } x; x.u = v; return (float)x.h;
}
static __device__ __forceinline__ h2 u2h2(u32 v) {
  union { u32 u; h2 h; } x; x.u = v; return x.h;
}
static __device__ __forceinline__ float dot2(u32 a, u32 b, float c) {
  return __builtin_amdgcn_fdot2(u2h2(a), u2h2(b), c, false);
}

// ---------------------------------------------------------------------------
// Transpose + cast 1024x1024 fp32 weights to bf16 in [N][K] (B^T) layout.
__global__ __launch_bounds__(256)
void wtrans_kernel(const float* __restrict__ w_in, const float* __restrict__ w_out,
                   u16* __restrict__ wt_in, u16* __restrict__ wt_out) {
  __shared__ float tile[32][33];
  const float* src = blockIdx.z ? w_out : w_in;
  u16* dst = blockIdx.z ? wt_out : wt_in;
  int n0 = blockIdx.x * 32, k0 = blockIdx.y * 32;
  int tx = threadIdx.x, ty = threadIdx.y;
#pragma unroll
  for (int i = 0; i < 32; i += 8)
    tile[ty + i][tx] = src[(size_t)(k0 + ty + i) * DD + n0 + tx];
  __syncthreads();
#pragma unroll
  for (int i = 0; i < 32; i += 8)
    dst[(size_t)(n0 + ty + i) * DD + k0 + tx] = f2bf(tile[tx][ty + i]);
}

// ---------------------------------------------------------------------------
// x fp32 -> bf16
__global__ __launch_bounds__(256)
void xcast_kernel(const float* __restrict__ x, u16* __restrict__ xb) {
  size_t i = (size_t)(blockIdx.x * 256 + threadIdx.x) * 4;
  float4 v = *(const float4*)(x + i);
  u16x4 o;
  o[0] = f2bf(v.x); o[1] = f2bf(v.y); o[2] = f2bf(v.z); o[3] = f2bf(v.w);
  *(u16x4*)(xb + i) = o;
}

// ---------------------------------------------------------------------------
// depthwise circular conv (K=4, pads 1/2) + SiLU -> f16. Block covers 16 t-rows
// (rolling register window: read amp 19/16 vs 4x in the row-per-block version).
__global__ __launch_bounds__(256)
void convsilu_kernel(const float* __restrict__ g, const float* __restrict__ ck,
                     const float* __restrict__ cb, u16* __restrict__ gp) {
  int blk = blockIdx.x;                 // 1024 blocks
  int b = blk >> 7, t0 = (blk & 127) * 16;
  int d = threadIdx.x * 4;
  const float* gb = g + (size_t)b * LL * DD;
  float4 k0 = *(const float4*)(ck + d);
  float4 k1 = *(const float4*)(ck + DD + d);
  float4 k2 = *(const float4*)(ck + 2 * DD + d);
  float4 k3 = *(const float4*)(ck + 3 * DD + d);
  float4 bi = *(const float4*)(cb + d);
#define LOADROW(t) (*(const float4*)(gb + (size_t)((t) & (LL - 1)) * DD + d))
  float4 r0 = LOADROW(t0 - 1), r1 = LOADROW(t0), r2 = LOADROW(t0 + 1);
#pragma unroll
  for (int i = 0; i < 16; ++i) {
    float4 r3 = LOADROW(t0 + i + 2);
    float v0 = r0.x*k0.x + r1.x*k1.x + r2.x*k2.x + r3.x*k3.x + bi.x;
    float v1 = r0.y*k0.y + r1.y*k1.y + r2.y*k2.y + r3.y*k3.y + bi.y;
    float v2 = r0.z*k0.z + r1.z*k1.z + r2.z*k2.z + r3.z*k3.z + bi.z;
    float v3 = r0.w*k0.w + r1.w*k1.w + r2.w*k2.w + r3.w*k3.w + bi.w;
    u16x4 o;
    o[0] = f2h(v0 / (1.f + expf(-v0)));
    o[1] = f2h(v1 / (1.f + expf(-v1)));
    o[2] = f2h(v2 / (1.f + expf(-v2)));
    o[3] = f2h(v3 / (1.f + expf(-v3)));
    *(u16x4*)(gp + (size_t)(b * LL + t0 + i) * DD + d) = o;
    r0 = r1; r1 = r2; r2 = r3;
  }
#undef LOADROW
}

// ---------------------------------------------------------------------------
// S4D kernel taps, f16, dot2-ready: Kd[(j*HH+h)*2+0] = half2(kre, -kim)
//                                   Kd[(j*HH+h)*2+1] = half2(kim,  kre)
__global__ __launch_bounds__(128)
void kgen_kernel(const float* __restrict__ ldk, const float* __restrict__ fq,
                 const float* __restrict__ wre, const float* __restrict__ wim,
                 u32* __restrict__ Kd) {
  int h = blockIdx.x, j = threadIdx.x;
  __shared__ float sr[NN], sf[NN], sa[NN], sb[NN];
  if (j < NN) {
    sr[j] = expf(ldk[h * NN + j]);  // decay rate
    sf[j] = fq[h * NN + j];
    sa[j] = wre[h * NN + j];
    sb[j] = wim[h * NN + j];
  }
  __syncthreads();
  float t = (float)j;
  float re = 0.f, im = 0.f;
  for (int n = 0; n < NN; ++n) {
    float e = expf(-sr[n] * t);
    float s, c;
    sincosf(sf[n] * t, &s, &c);
    re += e * (sa[n] * c - sb[n] * s);
    im += e * (sa[n] * s + sb[n] * c);
  }
  size_t o = ((size_t)j * HH + h) * 2;
  Kd[o]     = (u32)f2h(re)  | ((u32)f2h(-im) << 16);
  Kd[o + 1] = (u32)f2h(im)  | ((u32)f2h(re)  << 16);
}

// ---------------------------------------------------------------------------
// bf16 MFMA GEMM: C[M,N] = A[M,K] @ Bt[N,K]^T, 128x128 tile, BK=32, 4 waves 2x2.
// global_load_lds (width 16) staging; operands SWAPPED in the mfma so the 4
// regs of each acc quad land on 4 consecutive n -> vectorized stores.
// EPI=0: C *= gmul (f16), store f16.  EPI=1: store fp32.
template <int EPI>
__global__ __launch_bounds__(256)
void gemm_kernel(const u16* __restrict__ A, const u16* __restrict__ Bt,
                 const u16* __restrict__ gmul, void* __restrict__ out) {
  constexpr int K = DD;
  __shared__ __align__(16) u16 As[128 * 32];  // fragment-order: slot = frag*64+lane, 8 bf16
  __shared__ __align__(16) u16 Bs[128 * 32];
  int tid = threadIdx.x;
  int lane = tid & 63, w = tid >> 6;
  int wm = w & 1, wn = w >> 1;
  int lm = lane & 15, lk = lane >> 4;
  int n0 = blockIdx.x * 128, m0 = blockIdx.y * 128;

  f32x4 acc[4][4] = {};

  const u16* pa = A + (size_t)(m0 + lm) * K + lk * 8;
  const u16* pb = Bt + (size_t)(n0 + lm) * K + lk * 8;

  for (int k0 = 0; k0 < K; k0 += 32) {
    __syncthreads();
#pragma unroll
    for (int i = 0; i < 2; ++i) {
      int f = w + i * 4;  // fragment index 0..7 (rows f*16..f*16+15)
      __builtin_amdgcn_global_load_lds((gu32*)(pa + (size_t)f * 16 * K + k0),
                                       (lu32*)(As + (size_t)(i * 256 + w * 64) * 8), 16, 0, 0);
      __builtin_amdgcn_global_load_lds((gu32*)(pb + (size_t)f * 16 * K + k0),
                                       (lu32*)(Bs + (size_t)(i * 256 + w * 64) * 8), 16, 0, 0);
    }
    __syncthreads();
    s16x8 af[4], bfr[4];
#pragma unroll
    for (int i = 0; i < 4; ++i)
      af[i] = *(const s16x8*)(As + ((wm * 4 + i) * 64 + lane) * 8);
#pragma unroll
    for (int j = 0; j < 4; ++j)
      bfr[j] = *(const s16x8*)(Bs + ((wn * 4 + j) * 64 + lane) * 8);
#pragma unroll
    for (int i = 0; i < 4; ++i)
#pragma unroll
      for (int j = 0; j < 4; ++j)   // operands swapped: D[quad*4+reg <-> n][lane&15 <-> m]
        acc[i][j] = __builtin_amdgcn_mfma_f32_16x16x32_bf16(bfr[j], af[i], acc[i][j], 0, 0, 0);
  }

  int rb = (lane >> 4) * 4, mcol = lane & 15;
#pragma unroll
  for (int i = 0; i < 4; ++i) {
#pragma unroll
    for (int j = 0; j < 4; ++j) {
      int mg = m0 + wm * 64 + i * 16 + mcol;
      int ng = n0 + wn * 64 + j * 16 + rb;     // 4 consecutive n at ng..ng+3
      size_t idx = (size_t)mg * DD + ng;
      if (EPI == 0) {
        u16x4 gm = *(const u16x4*)(gmul + idx);
        u16x4 o;
#pragma unroll
        for (int r = 0; r < 4; ++r) o[r] = f2h(acc[i][j][r] * h2f(gm[r]));
        *(u16x4*)((u16*)out + idx) = o;
      } else {
        float4 o = make_float4(acc[i][j][0], acc[i][j][1], acc[i][j][2], acc[i][j][3]);
        *(float4*)((float*)out + idx) = o;
      }
    }
  }
}

// ---------------------------------------------------------------------------
// Truncated causal complex conv via v_dot2_f32_f16:
//   y[b,t,h] = sum_{j<128} K[h,j] * u_c[b,t-j,h]
// Block: one b, 32 h, 128 t. u window staged in LDS as packed half2 (re,im).
// K read from global (L1-broadcast across the 8 t-groups). Per (t,j):
//   acc.re = dot2((kre,-kim),(ure,uim));  acc.im = dot2((kim,kre),(ure,uim)).
__global__ __launch_bounds__(256, 4)
void ssmconv_kernel(const u16* __restrict__ u, const u32* __restrict__ Kd,
                    u16* __restrict__ y) {
  __shared__ u32 Us[256 * 32];   // [row s-rel][h]  (re lo16 | im hi16)   32 KB
  int tid = threadIdx.x;
  int t0 = blockIdx.x * 128;
  int h0 = blockIdx.y * 32;
  int b  = blockIdx.z;

  // stage u rows: row r <-> s = t0-128+r ; zero-fill s<0 (causal start)
  {
    int c = tid & 7, r0 = tid >> 3;
    for (int r = r0; r < 256; r += 32) {
      int s = t0 - 128 + r;
      u32x4 pk = {};
      if (s >= 0) {
        const u16* ur = u + (size_t)(b * LL + s) * DD;
        u16x4 re = *(const u16x4*)(ur + h0 + c * 4);
        u16x4 im = *(const u16x4*)(ur + h0 + 512 + c * 4);
        pk[0] = re[0] | ((u32)im[0] << 16);
        pk[1] = re[1] | ((u32)im[1] << 16);
        pk[2] = re[2] | ((u32)im[2] << 16);
        pk[3] = re[3] | ((u32)im[3] << 16);
      }
      *(u32x4*)(Us + r * 32 + c * 4) = pk;
    }
  }
  __syncthreads();

  int h = tid & 31, tg = tid >> 5;
  int tl0 = tg * 16;
  float accr[16], acci[16];
#pragma unroll
  for (int i = 0; i < 16; ++i) { accr[i] = 0.f; acci[i] = 0.f; }

#pragma unroll 1
  for (int jb = 0; jb < 8; ++jb) {
    // K taps for this j-block (uniform across tg -> L1 broadcast)
    u32x2 kk[16];
#pragma unroll
    for (int jj = 0; jj < 16; ++jj)
      kk[jj] = *(const u32x2*)(Kd + ((size_t)(jb * 16 + jj) * HH + h0 + h) * 2);
    // u window: W[i] = u at m = jb*16 - 15 + i  (row = 143 + tl0 - jb*16 - i)
    u32 W[31];
    int rbase = 143 + tl0 - jb * 16;
#pragma unroll
    for (int i = 0; i < 31; ++i)
      W[i] = Us[(rbase - i) * 32 + h];
#pragma unroll
    for (int jj = 0; jj < 16; ++jj) {
#pragma unroll
      for (int toff = 0; toff < 16; ++toff) {
        u32 up = W[15 + jj - toff];
        accr[toff] = dot2(kk[jj][0], up, accr[toff]);
        acci[toff] = dot2(kk[jj][1], up, acci[toff]);
      }
    }
  }
  u16* yr = y + (size_t)(b * LL + t0 + tl0) * DD;
#pragma unroll
  for (int toff = 0; toff < 16; ++toff) {
    yr[(size_t)toff * DD + h0 + h]       = f2bf(accr[toff]);  // real -> ch [0,512)
    yr[(size_t)toff * DD + h0 + 512 + h] = f2bf(acci[toff]);  // imag -> ch [512,1024)
  }
}

// ---------------------------------------------------------------------------
extern "C" void kernel_launch(void* const* d_in, const int* in_sizes, int n_in,
                              void* d_out, int out_size, void* d_ws, size_t ws_size,
                              hipStream_t stream) {
  (void)in_sizes; (void)n_in; (void)out_size; (void)ws_size;
  const float* x    = (const float*)d_in[0];
  const float* g    = (const float*)d_in[1];
  const float* win  = (const float*)d_in[2];
  const float* ck   = (const float*)d_in[3];
  const float* cb   = (const float*)d_in[4];
  const float* ldk  = (const float*)d_in[5];
  const float* fq   = (const float*)d_in[6];
  const float* wre  = (const float*)d_in[7];
  const float* wim  = (const float*)d_in[8];
  const float* wout = (const float*)d_in[9];

  char* ws = (char*)d_ws;
  const size_t SZ = (size_t)MT * DD * 2;           // 32 MB per 16-bit tensor
  u16* xb  = (u16*)(ws);                           // bf16 x
  u16* gp  = (u16*)(ws + SZ);                      // f16  g' (silu(conv))
  u16* ub  = (u16*)(ws + 2 * SZ);                  // f16  u
  u16* yb  = (u16*)(ws + 3 * SZ);                  // bf16 y
  u16* wti = (u16*)(ws + 4 * SZ);                  // bf16 w_in^T
  u16* wto = (u16*)(ws + 4 * SZ + (1 << 21));      // bf16 w_out^T
  u32* Kd  = (u32*)(ws + 4 * SZ + (2 << 21));      // f16 taps, 512 KB

  wtrans_kernel<<<dim3(32, 32, 2), dim3(32, 8), 0, stream>>>(win, wout, wti, wto);
  xcast_kernel<<<dim3(MT * DD / 1024), dim3(256), 0, stream>>>(x, xb);
  convsilu_kernel<<<dim3(MT / 16), dim3(256), 0, stream>>>(g, ck, cb, gp);
  kgen_kernel<<<dim3(HH), dim3(128), 0, stream>>>(ldk, fq, wre, wim, Kd);
  gemm_kernel<0><<<dim3(8, 128), dim3(256), 0, stream>>>(xb, wti, gp, ub);
  ssmconv_kernel<<<dim3(16, 16, 8), dim3(256), 0, stream>>>(ub, Kd, yb);
  gemm_kernel<1><<<dim3(8, 128), dim3(256), 0, stream>>>(yb, wto, nullptr, d_out);
}